// Round 2
// baseline (222.064 us; speedup 1.0000x reference)
//
#include <hip/hip_runtime.h>
#include <hip/hip_bf16.h>

#define B_ 2
#define N_ 2048
#define E_ 1024
#define H_ 16
#define D_ 64
#define M_TOT (B_*N_)   // 4096

typedef __attribute__((ext_vector_type(8))) short bf16x8;
typedef __attribute__((ext_vector_type(4))) float f32x4;

__device__ __forceinline__ unsigned short f2bf(float f) {
    unsigned int u = __float_as_uint(f);
    u += 0x7fff + ((u >> 16) & 1);   // round-to-nearest-even
    return (unsigned short)(u >> 16);
}

// async global->LDS, 16B per lane; dst is wave-uniform base + lane*16
__device__ __forceinline__ void gload16(const void* g, void* l) {
    __builtin_amdgcn_global_load_lds(
        (const __attribute__((address_space(1))) unsigned int*)g,
        (__attribute__((address_space(3))) unsigned int*)l, 16, 0, 0);
}

// ---------------- LayerNorm -> bf16, PRE-SWIZZLED rows ----------------
// Xn[row][byte'] where byte' = byte ^ ((row&7)<<4) within each 128B chunk.
__global__ __launch_bounds__(256) void ln_kernel(
    const float* __restrict__ Q, const float* __restrict__ K,
    const float* __restrict__ V, const float* __restrict__ gamma,
    const float* __restrict__ beta, unsigned short* __restrict__ Xn)
{
    const int row = blockIdx.x;          // 0..4095
    const int s   = blockIdx.y;          // 0: Q, 1: K, 2: V
    const float* X = (s == 0) ? Q : (s == 1) ? K : V;
    const int tid = threadIdx.x;
    const float4 x = ((const float4*)(X + (size_t)row * E_))[tid];
    float sum = x.x + x.y + x.z + x.w;
    float sq  = x.x*x.x + x.y*x.y + x.z*x.z + x.w*x.w;
    #pragma unroll
    for (int off = 32; off > 0; off >>= 1) {
        sum += __shfl_down(sum, off);
        sq  += __shfl_down(sq,  off);
    }
    __shared__ float red[8];
    const int wid = tid >> 6;
    if ((tid & 63) == 0) { red[wid] = sum; red[4 + wid] = sq; }
    __syncthreads();
    if (tid == 0) {
        float s0 = red[0] + red[1] + red[2] + red[3];
        float q0 = red[4] + red[5] + red[6] + red[7];
        red[0] = s0 * (1.0f / E_);
        red[4] = q0 * (1.0f / E_);
    }
    __syncthreads();
    const float mean = red[0];
    const float var  = red[4] - mean * mean;
    const float inv  = rsqrtf(var + 1e-5f);
    const float4 g = ((const float4*)gamma)[tid];
    const float4 b = ((const float4*)beta)[tid];
    ushort4 o;
    o.x = f2bf((x.x - mean) * inv * g.x + b.x);
    o.y = f2bf((x.y - mean) * inv * g.y + b.y);
    o.z = f2bf((x.z - mean) * inv * g.z + b.z);
    o.w = f2bf((x.w - mean) * inv * g.w + b.w);
    const int bo = 8 * tid;
    const int bs = (bo & ~127) | ((bo & 127) ^ ((row & 7) << 4));
    char* rowp = (char*)(Xn + (size_t)s * M_TOT * E_ + (size_t)row * E_);
    *(ushort4*)(rowp + bs) = o;
}

// ------- Weight transpose + bf16, PRE-SWIZZLED: Wt[s][n][k'] = W_s[k][n] -----
__global__ __launch_bounds__(256) void wt_kernel(
    const float* __restrict__ Wq, const float* __restrict__ Wk,
    const float* __restrict__ Wv, unsigned short* __restrict__ Wt)
{
    const int s = blockIdx.z;
    const float* W = (s == 0) ? Wq : (s == 1) ? Wk : Wv;
    __shared__ float tile[32][33];
    const int tx = threadIdx.x, ty = threadIdx.y;   // 32 x 8
    const int n0 = blockIdx.x * 32, k0 = blockIdx.y * 32;
    #pragma unroll
    for (int i = 0; i < 4; i++)
        tile[ty + 8*i][tx] = W[(size_t)(k0 + ty + 8*i) * E_ + n0 + tx];
    __syncthreads();
    unsigned short* dst = Wt + (size_t)s * E_ * E_;
    #pragma unroll
    for (int i = 0; i < 4; i++) {
        const int n = n0 + ty + 8*i;
        const int bo = 2 * (k0 + tx);
        const int bs = (bo & ~127) | ((bo & 127) ^ ((n & 7) << 4));
        *(unsigned short*)((char*)(dst + (size_t)n * E_) + bs) =
            f2bf(tile[tx][ty + 8*i]);
    }
}

// --- GEMM: C = Xn[s] @ W_s + b_s -> head layout bf16 ---   (R23-proven)
//   128x128 tile, 4 waves in a 1x4 grid -> per-wave 128 rows x 32 cols.
//   A: gload_lds dbuf (32KB LDS -> 3 blocks/CU, grid 768, T1 map).
//   B: direct global->reg, issued immediately pre-barrier.
//   s=2 epilogue: 4 consecutive nseq packed into one 8B store.
__global__ __launch_bounds__(256, 3) void gemm_kernel(
    const unsigned short* __restrict__ Xn, const unsigned short* __restrict__ Wt,
    const float* __restrict__ bq, const float* __restrict__ bk,
    const float* __restrict__ bv, unsigned short* __restrict__ QKVh)
{
    const int bid = blockIdx.x;
    const int wk  = (bid & 7) * 96 + (bid >> 3);   // bijective, 768 = 8*96
    const int s   = wk >> 8;            // 0..2
    const int rem = wk & 255;
    const int m0  = (rem >> 3) * 128;
    const int n0  = (rem & 7) * 128;
    const float* bias = (s == 0) ? bq : (s == 1) ? bk : bv;
    const unsigned short* A  = Xn + (size_t)s * M_TOT * E_;
    const unsigned short* Bw = Wt + (size_t)s * E_ * E_;
    unsigned short* out = QKVh + (size_t)s * M_TOT * E_;
    const int tid = threadIdx.x;
    const int lane = tid & 63;
    const int w = tid >> 6;             // 0..3  (wave = 32-col panel)
    const int l15 = lane & 15, lhi = lane >> 4;

    __shared__ unsigned short Al[2][128][64];   // 16KB per buf

    const int srow = lane >> 3;        // 0..7
    const int scol = (lane & 7) * 8;   // elem col (source is pre-swizzled)
    const int rx = (l15 & 7) << 4;     // read-side XOR

    // B fragment base: row n0 + w*32 + n*16 + l15  (row&7 == l15&7 -> rx)
    const char* bbase = (const char*)Bw + (size_t)(n0 + w*32 + l15) * (E_ * 2);

    f32x4 acc[8][2];
    #pragma unroll
    for (int m = 0; m < 8; m++)
        #pragma unroll
        for (int n = 0; n < 2; n++)
            acc[m][n] = (f32x4){0.f, 0.f, 0.f, 0.f};

    // stage A k-tile kt into buffer b: per wave 4 gload16 (32 rows)
    #define STAGEA(b_, kt_) do {                                             \
        const int k0_ = (kt_) * 64;                                          \
        _Pragma("unroll")                                                    \
        for (int ii = 0; ii < 4; ii++) {                                     \
            const int r_ = w*32 + ii*8;                                      \
            gload16(A + (size_t)(m0 + r_ + srow) * E_ + k0_ + scol,          \
                    &Al[b_][r_][0]);                                         \
        }                                                                    \
    } while (0)

    STAGEA(0, 0);
    for (int kt = 0; kt < 16; kt++) {
        const int buf = kt & 1;
        // B fragments for this k-step: direct from global (L2-hot)
        bf16x8 bfr[2][2];
        #pragma unroll
        for (int ks = 0; ks < 2; ks++)
            #pragma unroll
            for (int n = 0; n < 2; n++)
                bfr[ks][n] = *(const bf16x8*)(bbase + (size_t)n * 16 * (E_ * 2)
                               + kt*128 + ((ks*64 + lhi*16) ^ rx));
        __syncthreads();                 // A buf staged (vmcnt drained here)
        if (kt + 1 < 16) STAGEA(buf ^ 1, kt + 1);  // async, flies during compute
        const char* ab = (const char*)Al[buf];
        #pragma unroll
        for (int ks = 0; ks < 2; ks++) {
            #pragma unroll
            for (int m = 0; m < 8; m++) {
                bf16x8 af = *(const bf16x8*)(ab
                        + (m*16 + l15)*128 + ((ks*64 + lhi*16) ^ rx));
                #pragma unroll
                for (int n = 0; n < 2; n++)
                    acc[m][n] = __builtin_amdgcn_mfma_f32_16x16x32_bf16(
                        af, bfr[ks][n], acc[m][n], 0, 0, 0);
            }
        }
    }
    #undef STAGEA

    const float scale = (s == 0) ? 0.18033688011112042f : 1.0f;
    #pragma unroll
    for (int n = 0; n < 2; n++) {
        const int gn = n0 + w*32 + n*16 + l15;
        const float bv_ = bias[gn];
        const int h = gn >> 6, d = gn & 63;
        #pragma unroll
        for (int m = 0; m < 8; m++) {
            const int gmBase = m0 + m*16 + lhi*4;
            if (s == 2) {
                // 4 consecutive nseq -> one packed 8B store
                const int bb2 = gmBase >> 11, nseq = gmBase & 2047;
                ushort4 pk;
                pk.x = f2bf(acc[m][n][0] + bv_);
                pk.y = f2bf(acc[m][n][1] + bv_);
                pk.z = f2bf(acc[m][n][2] + bv_);
                pk.w = f2bf(acc[m][n][3] + bv_);
                *(ushort4*)(out + ((size_t)(bb2*H_ + h) * D_ + d) * N_ + nseq)
                    = pk;
            } else {
                #pragma unroll
                for (int j = 0; j < 4; j++) {
                    const int gm = gmBase + j;
                    const int bb2 = gm >> 11, nseq = gm & 2047;
                    out[((size_t)(bb2*H_ + h) * N_ + nseq) * D_ + d] =
                        f2bf((acc[m][n][j] + bv_) * scale);
                }
            }
        }
    }
}

// ---------------- Flash attention (causal) + residual ----------------
// KV-SPLIT rewrite: 2048 blocks x 256 threads (4 waves).  Each block owns
// 32 q-rows of one head; wave w processes kv tiles t = w, w+4, ... (stripe
// partition -- no K/V read duplication).  Compute loop is BARRIER-FREE:
// K/V fragments read direct from global (L2-resident: bid%8 -> bh%8
// confines each XCD to 4 heads = 2MB < 4MB L2), K prefetched one owned
// tile (=4 kv tiles) ahead, P through per-wave private 4KB swizzled LDS.
// UNNORMALIZED softmax (p = exp2(s), no max state) makes the kv-stripe
// merge pure addition: one LDS exchange + 2 barriers per block TOTAL.
// l accumulated by ones-row MFMA (zero VALU row-sum work).
// Occupancy: 8192 waves (vs 2048 in prev rev); 4 waves/SIMD VGPR cap,
// LDS 34.8KB -> 4 blocks/CU matches.
__global__ __launch_bounds__(256, 4) void attn_kernel(
    const unsigned short* __restrict__ QKVh, const float* __restrict__ Qin,
    float* __restrict__ out)
{
    const int bid = blockIdx.x;          // 0..2047
    const int bh  = bid & 31;            // head-batch (bh%8 == XCD)
    const int qg  = 63 - (bid >> 5);     // 32-row q-group, heavy jobs first
    const int q0  = qg * 32;
    const int nt  = (qg >> 1) + 1;       // causal tile count
    const int tdiag = nt - 1;            // diagonal tile (== q0>>6)
    const int tid  = threadIdx.x;
    const int lane = tid & 63;
    const int w    = tid >> 6;           // 0..3 = kv stripe
    const int l15 = lane & 15, lhi = lane >> 4;
    const int rxor = (l15 & 7) << 4;

    const size_t headOff = (size_t)bh * N_ * D_;
    const unsigned short* qp = QKVh + headOff;                      // [N][D]
    const unsigned short* kh = QKVh + (size_t)M_TOT * E_ + headOff; // [N][D]
    const unsigned short* vh = QKVh + (size_t)2 * M_TOT * E_ + headOff; // [D][N]

    __shared__ union {
        unsigned short P[4][2048];       // per-wave P buffer (4KB each)
        struct {
            f32x4 Mo[4][8][64];          // partial O  [wave][qh*4+n][lane]
            float Ml[4][2][64];          // partial l  [wave][qh][lane]
        } m;
    } sm;                                 // 34816 B

    // Q fragments: B-operand, col = q-row (q0 + qh*16 + l15), k = d
    bf16x8 qf[2][2];
    #pragma unroll
    for (int qh = 0; qh < 2; qh++)
        #pragma unroll
        for (int ks = 0; ks < 2; ks++)
            qf[qh][ks] = *(const bf16x8*)(qp
                + (size_t)(q0 + qh*16 + l15) * D_ + ks*32 + lhi*8);

    // per-lane intra-tile byte offsets
    // K frag (ks,n) @ tile t: (t*64 + n*16 + l15)*128 + ks*64 + lhi*16
    const char* kbase = (const char*)kh + l15*128 + lhi*16;
    // V frag (ks,n) @ tile t: (n*16 + l15)*4096 + t*128 + ks*64 + lhi*16
    const char* vbase = (const char*)vh + l15*4096 + lhi*16;

    const f32x4 fz = {0.f, 0.f, 0.f, 0.f};
    f32x4 o[2][4], ol[2];
    #pragma unroll
    for (int qh = 0; qh < 2; qh++) {
        ol[qh] = fz;
        #pragma unroll
        for (int n = 0; n < 4; n++) o[qh][n] = fz;
    }
    bf16x8 ones;
    #pragma unroll
    for (int i = 0; i < 8; i++) ones[i] = (short)0x3F80;   // bf16 1.0

    // preload K for this wave's first tile
    bf16x8 kb[2][4];
    if (w < nt) {
        const char* kt0 = kbase + (size_t)w * 8192;
        #pragma unroll
        for (int ks = 0; ks < 2; ks++)
            #pragma unroll
            for (int n = 0; n < 4; n++)
                kb[ks][n] = *(const bf16x8*)(kt0 + n*2048 + ks*64);
    }

    char* pw = (char*)sm.P[w];

    #pragma unroll 1
    for (int t = w; t < nt; t += 4) {
        // V for this tile: issued now, consumed after QK+softmax (~covered)
        const char* vt = vbase + t*128;
        bf16x8 vb[2][4];
        #pragma unroll
        for (int ks = 0; ks < 2; ks++)
            #pragma unroll
            for (int n = 0; n < 4; n++)
                vb[ks][n] = *(const bf16x8*)(vt + n*65536 + ks*64);

        // QK^T swapped: S^T = K * Q^T  (lane: q = l15, kv = n*16+lhi*4+j)
        f32x4 sf[2][4];
        __builtin_amdgcn_s_setprio(1);
        #pragma unroll
        for (int qh = 0; qh < 2; qh++)
            #pragma unroll
            for (int n = 0; n < 4; n++)
                sf[qh][n] = __builtin_amdgcn_mfma_f32_16x16x32_bf16(
                    kb[1][n], qf[qh][1],
                    __builtin_amdgcn_mfma_f32_16x16x32_bf16(
                        kb[0][n], qf[qh][0], fz, 0, 0, 0), 0, 0, 0);
        __builtin_amdgcn_s_setprio(0);

        if (t == tdiag) {   // causal mask, diagonal tile only
            #pragma unroll
            for (int qh = 0; qh < 2; qh++) {
                const int qr = q0 + qh*16 + l15;
                #pragma unroll
                for (int n = 0; n < 4; n++)
                    #pragma unroll
                    for (int j = 0; j < 4; j++) {
                        const int kvc = t*64 + n*16 + lhi*4 + j;
                        sf[qh][n][j] = (kvc > qr) ? -1e30f : sf[qh][n][j];
                    }
            }
        }

        // p = exp2(s); pack pairs -> bf16, store to swizzled P rows
        #pragma unroll
        for (int qh = 0; qh < 2; qh++) {
            const int prow = (qh*16 + l15) * 128;
            #pragma unroll
            for (int n = 0; n < 4; n++) {
                unsigned int u0 = __float_as_uint(exp2f(sf[qh][n][0])) + 0x8000u;
                unsigned int u1 = __float_as_uint(exp2f(sf[qh][n][1])) + 0x8000u;
                unsigned int u2 = __float_as_uint(exp2f(sf[qh][n][2])) + 0x8000u;
                unsigned int u3 = __float_as_uint(exp2f(sf[qh][n][3])) + 0x8000u;
                uint2 pk;
                pk.x = __builtin_amdgcn_perm(u1, u0, 0x07060302u);
                pk.y = __builtin_amdgcn_perm(u3, u2, 0x07060302u);
                *(uint2*)(pw + prow + ((n*32 + lhi*8) ^ rxor)) = pk;
            }
        }

        // prefetch K for next owned tile (t+4); flies during PV
        if (t + 4 < nt) {
            const char* kt = kbase + (size_t)(t + 4) * 8192;
            #pragma unroll
            for (int ks = 0; ks < 2; ks++)
                #pragma unroll
                for (int n = 0; n < 4; n++)
                    kb[ks][n] = *(const bf16x8*)(kt + n*2048 + ks*64);
        }

        // PV: O^T += V^T * P^T ; l += ones-row * P^T (same pb operands)
        #pragma unroll
        for (int ks = 0; ks < 2; ks++) {
            bf16x8 pb[2];
            #pragma unroll
            for (int qh = 0; qh < 2; qh++)
                pb[qh] = *(const bf16x8*)(pw + (qh*16 + l15)*128
                                             + ((ks*64 + lhi*16) ^ rxor));
            __builtin_amdgcn_s_setprio(1);
            #pragma unroll
            for (int n = 0; n < 4; n++) {
                o[0][n] = __builtin_amdgcn_mfma_f32_16x16x32_bf16(
                    vb[ks][n], pb[0], o[0][n], 0, 0, 0);
                o[1][n] = __builtin_amdgcn_mfma_f32_16x16x32_bf16(
                    vb[ks][n], pb[1], o[1][n], 0, 0, 0);
            }
            ol[0] = __builtin_amdgcn_mfma_f32_16x16x32_bf16(
                ones, pb[0], ol[0], 0, 0, 0);
            ol[1] = __builtin_amdgcn_mfma_f32_16x16x32_bf16(
                ones, pb[1], ol[1], 0, 0, 0);
            __builtin_amdgcn_s_setprio(0);
        }
    }

    // ---- merge kv stripes (pure addition; unnormalized softmax) ----
    __syncthreads();                     // all P reads done (merge aliases P)
    #pragma unroll
    for (int qh = 0; qh < 2; qh++) {
        #pragma unroll
        for (int n = 0; n < 4; n++)
            sm.m.Mo[w][qh*4 + n][lane] = o[qh][n];
        sm.m.Ml[w][qh][lane] = ol[qh][0];   // all acc rows equal; [0] = l(q)
    }
    __syncthreads();

    // epilogue: wave w handles fragment pairs p = 2w, 2w+1  (p = qh*4+n)
    const int bb = bh >> 4, hh = bh & 15;
    #pragma unroll
    for (int pi = 0; pi < 2; pi++) {
        const int p  = 2*w + pi;
        const int qh = p >> 2, n = p & 3;
        f32x4 acc = sm.m.Mo[0][p][lane];
        float ls  = sm.m.Ml[0][qh][lane];
        #pragma unroll
        for (int w2 = 1; w2 < 4; w2++) {
            acc += sm.m.Mo[w2][p][lane];
            ls  += sm.m.Ml[w2][qh][lane];
        }
        const float linv = 1.0f / ls;
        const int qr = q0 + qh*16 + l15;
        const int d0 = n*16 + lhi*4;
        const size_t idx = ((size_t)(bb * N_ + qr)) * E_ + hh * D_ + d0;
        const float4 r = *(const float4*)(Qin + idx);
        float4 ov;
        ov.x = acc[0] * linv + r.x;
        ov.y = acc[1] * linv + r.y;
        ov.z = acc[2] * linv + r.z;
        ov.w = acc[3] * linv + r.w;
        *(float4*)(out + idx) = ov;
    }
}

extern "C" void kernel_launch(void* const* d_in, const int* in_sizes, int n_in,
                              void* d_out, int out_size, void* d_ws, size_t ws_size,
                              hipStream_t stream) {
    const float* Q     = (const float*)d_in[0];
    const float* K     = (const float*)d_in[1];
    const float* V     = (const float*)d_in[2];
    // d_in[3] = mask (causal, implemented analytically) -- unused
    const float* Wq    = (const float*)d_in[4];
    const float* bq    = (const float*)d_in[5];
    const float* Wk    = (const float*)d_in[6];
    const float* bk    = (const float*)d_in[7];
    const float* Wv    = (const float*)d_in[8];
    const float* bv    = (const float*)d_in[9];
    const float* gamma = (const float*)d_in[10];
    const float* beta  = (const float*)d_in[11];
    float* out = (float*)d_out;

    char* ws = (char*)d_ws;
    unsigned short* Xn   = (unsigned short*)ws;                    // 3*4096*1024 bf16 = 25,165,824 B
    unsigned short* Wt   = (unsigned short*)(ws + 25165824);       // 3*1024*1024 bf16 =  6,291,456 B
    unsigned short* QKVh = (unsigned short*)(ws + 31457280);       // 3*4096*1024 bf16 = 25,165,824 B

    ln_kernel  <<<dim3(4096, 3),   256,        0, stream>>>(Q, K, V, gamma, beta, Xn);
    wt_kernel  <<<dim3(32, 32, 3), dim3(32,8), 0, stream>>>(Wq, Wk, Wv, Wt);
    gemm_kernel<<<dim3(768),       256,        0, stream>>>(Xn, Wt, bq, bk, bv, QKVh);
    attn_kernel<<<dim3(2048),      256,        0, stream>>>(QKVh, Q, out);
}

// Round 3
// 119.902 us; speedup vs baseline: 1.8520x; 1.8520x over previous
//
#include <hip/hip_runtime.h>
#include <hip/hip_bf16.h>

#define B_ 2
#define N_ 2048
#define E_ 1024
#define H_ 16
#define D_ 64
#define M_TOT (B_*N_)   // 4096

typedef __attribute__((ext_vector_type(8))) short bf16x8;
typedef __attribute__((ext_vector_type(4))) float f32x4;

__device__ __forceinline__ unsigned short f2bf(float f) {
    unsigned int u = __float_as_uint(f);
    u += 0x7fff + ((u >> 16) & 1);   // round-to-nearest-even
    return (unsigned short)(u >> 16);
}

// async global->LDS, 16B per lane; dst is wave-uniform base + lane*16
__device__ __forceinline__ void gload16(const void* g, void* l) {
    __builtin_amdgcn_global_load_lds(
        (const __attribute__((address_space(1))) unsigned int*)g,
        (__attribute__((address_space(3))) unsigned int*)l, 16, 0, 0);
}

// ---------------- LayerNorm -> bf16, PRE-SWIZZLED rows ----------------
// Xn[row][byte'] where byte' = byte ^ ((row&7)<<4) within each 128B chunk.
__global__ __launch_bounds__(256) void ln_kernel(
    const float* __restrict__ Q, const float* __restrict__ K,
    const float* __restrict__ V, const float* __restrict__ gamma,
    const float* __restrict__ beta, unsigned short* __restrict__ Xn)
{
    const int row = blockIdx.x;          // 0..4095
    const int s   = blockIdx.y;          // 0: Q, 1: K, 2: V
    const float* X = (s == 0) ? Q : (s == 1) ? K : V;
    const int tid = threadIdx.x;
    const float4 x = ((const float4*)(X + (size_t)row * E_))[tid];
    float sum = x.x + x.y + x.z + x.w;
    float sq  = x.x*x.x + x.y*x.y + x.z*x.z + x.w*x.w;
    #pragma unroll
    for (int off = 32; off > 0; off >>= 1) {
        sum += __shfl_down(sum, off);
        sq  += __shfl_down(sq,  off);
    }
    __shared__ float red[8];
    const int wid = tid >> 6;
    if ((tid & 63) == 0) { red[wid] = sum; red[4 + wid] = sq; }
    __syncthreads();
    if (tid == 0) {
        float s0 = red[0] + red[1] + red[2] + red[3];
        float q0 = red[4] + red[5] + red[6] + red[7];
        red[0] = s0 * (1.0f / E_);
        red[4] = q0 * (1.0f / E_);
    }
    __syncthreads();
    const float mean = red[0];
    const float var  = red[4] - mean * mean;
    const float inv  = rsqrtf(var + 1e-5f);
    const float4 g = ((const float4*)gamma)[tid];
    const float4 b = ((const float4*)beta)[tid];
    ushort4 o;
    o.x = f2bf((x.x - mean) * inv * g.x + b.x);
    o.y = f2bf((x.y - mean) * inv * g.y + b.y);
    o.z = f2bf((x.z - mean) * inv * g.z + b.z);
    o.w = f2bf((x.w - mean) * inv * g.w + b.w);
    const int bo = 8 * tid;
    const int bs = (bo & ~127) | ((bo & 127) ^ ((row & 7) << 4));
    char* rowp = (char*)(Xn + (size_t)s * M_TOT * E_ + (size_t)row * E_);
    *(ushort4*)(rowp + bs) = o;
}

// ------- Weight transpose + bf16, PRE-SWIZZLED: Wt[s][n][k'] = W_s[k][n] -----
__global__ __launch_bounds__(256) void wt_kernel(
    const float* __restrict__ Wq, const float* __restrict__ Wk,
    const float* __restrict__ Wv, unsigned short* __restrict__ Wt)
{
    const int s = blockIdx.z;
    const float* W = (s == 0) ? Wq : (s == 1) ? Wk : Wv;
    __shared__ float tile[32][33];
    const int tx = threadIdx.x, ty = threadIdx.y;   // 32 x 8
    const int n0 = blockIdx.x * 32, k0 = blockIdx.y * 32;
    #pragma unroll
    for (int i = 0; i < 4; i++)
        tile[ty + 8*i][tx] = W[(size_t)(k0 + ty + 8*i) * E_ + n0 + tx];
    __syncthreads();
    unsigned short* dst = Wt + (size_t)s * E_ * E_;
    #pragma unroll
    for (int i = 0; i < 4; i++) {
        const int n = n0 + ty + 8*i;
        const int bo = 2 * (k0 + tx);
        const int bs = (bo & ~127) | ((bo & 127) ^ ((n & 7) << 4));
        *(unsigned short*)((char*)(dst + (size_t)n * E_) + bs) =
            f2bf(tile[tx][ty + 8*i]);
    }
}

// --- GEMM: C = Xn[s] @ W_s + b_s -> head layout bf16 ---   (R23-proven)
//   128x128 tile, 4 waves in a 1x4 grid -> per-wave 128 rows x 32 cols.
//   A: gload_lds dbuf (32KB LDS -> 3 blocks/CU, grid 768, T1 map).
//   B: direct global->reg, issued immediately pre-barrier.
//   s=2 epilogue: 4 consecutive nseq packed into one 8B store.
__global__ __launch_bounds__(256, 3) void gemm_kernel(
    const unsigned short* __restrict__ Xn, const unsigned short* __restrict__ Wt,
    const float* __restrict__ bq, const float* __restrict__ bk,
    const float* __restrict__ bv, unsigned short* __restrict__ QKVh)
{
    const int bid = blockIdx.x;
    const int wk  = (bid & 7) * 96 + (bid >> 3);   // bijective, 768 = 8*96
    const int s   = wk >> 8;            // 0..2
    const int rem = wk & 255;
    const int m0  = (rem >> 3) * 128;
    const int n0  = (rem & 7) * 128;
    const float* bias = (s == 0) ? bq : (s == 1) ? bk : bv;
    const unsigned short* A  = Xn + (size_t)s * M_TOT * E_;
    const unsigned short* Bw = Wt + (size_t)s * E_ * E_;
    unsigned short* out = QKVh + (size_t)s * M_TOT * E_;
    const int tid = threadIdx.x;
    const int lane = tid & 63;
    const int w = tid >> 6;             // 0..3  (wave = 32-col panel)
    const int l15 = lane & 15, lhi = lane >> 4;

    __shared__ unsigned short Al[2][128][64];   // 16KB per buf

    const int srow = lane >> 3;        // 0..7
    const int scol = (lane & 7) * 8;   // elem col (source is pre-swizzled)
    const int rx = (l15 & 7) << 4;     // read-side XOR

    // B fragment base: row n0 + w*32 + n*16 + l15  (row&7 == l15&7 -> rx)
    const char* bbase = (const char*)Bw + (size_t)(n0 + w*32 + l15) * (E_ * 2);

    f32x4 acc[8][2];
    #pragma unroll
    for (int m = 0; m < 8; m++)
        #pragma unroll
        for (int n = 0; n < 2; n++)
            acc[m][n] = (f32x4){0.f, 0.f, 0.f, 0.f};

    // stage A k-tile kt into buffer b: per wave 4 gload16 (32 rows)
    #define STAGEA(b_, kt_) do {                                             \
        const int k0_ = (kt_) * 64;                                          \
        _Pragma("unroll")                                                    \
        for (int ii = 0; ii < 4; ii++) {                                     \
            const int r_ = w*32 + ii*8;                                      \
            gload16(A + (size_t)(m0 + r_ + srow) * E_ + k0_ + scol,          \
                    &Al[b_][r_][0]);                                         \
        }                                                                    \
    } while (0)

    STAGEA(0, 0);
    for (int kt = 0; kt < 16; kt++) {
        const int buf = kt & 1;
        // B fragments for this k-step: direct from global (L2-hot)
        bf16x8 bfr[2][2];
        #pragma unroll
        for (int ks = 0; ks < 2; ks++)
            #pragma unroll
            for (int n = 0; n < 2; n++)
                bfr[ks][n] = *(const bf16x8*)(bbase + (size_t)n * 16 * (E_ * 2)
                               + kt*128 + ((ks*64 + lhi*16) ^ rx));
        __syncthreads();                 // A buf staged (vmcnt drained here)
        if (kt + 1 < 16) STAGEA(buf ^ 1, kt + 1);  // async, flies during compute
        const char* ab = (const char*)Al[buf];
        #pragma unroll
        for (int ks = 0; ks < 2; ks++) {
            #pragma unroll
            for (int m = 0; m < 8; m++) {
                bf16x8 af = *(const bf16x8*)(ab
                        + (m*16 + l15)*128 + ((ks*64 + lhi*16) ^ rx));
                #pragma unroll
                for (int n = 0; n < 2; n++)
                    acc[m][n] = __builtin_amdgcn_mfma_f32_16x16x32_bf16(
                        af, bfr[ks][n], acc[m][n], 0, 0, 0);
            }
        }
    }
    #undef STAGEA

    const float scale = (s == 0) ? 0.18033688011112042f : 1.0f;
    #pragma unroll
    for (int n = 0; n < 2; n++) {
        const int gn = n0 + w*32 + n*16 + l15;
        const float bv_ = bias[gn];
        const int h = gn >> 6, d = gn & 63;
        #pragma unroll
        for (int m = 0; m < 8; m++) {
            const int gmBase = m0 + m*16 + lhi*4;
            if (s == 2) {
                // 4 consecutive nseq -> one packed 8B store
                const int bb2 = gmBase >> 11, nseq = gmBase & 2047;
                ushort4 pk;
                pk.x = f2bf(acc[m][n][0] + bv_);
                pk.y = f2bf(acc[m][n][1] + bv_);
                pk.z = f2bf(acc[m][n][2] + bv_);
                pk.w = f2bf(acc[m][n][3] + bv_);
                *(ushort4*)(out + ((size_t)(bb2*H_ + h) * D_ + d) * N_ + nseq)
                    = pk;
            } else {
                #pragma unroll
                for (int j = 0; j < 4; j++) {
                    const int gm = gmBase + j;
                    const int bb2 = gm >> 11, nseq = gm & 2047;
                    out[((size_t)(bb2*H_ + h) * N_ + nseq) * D_ + d] =
                        f2bf((acc[m][n][j] + bv_) * scale);
                }
            }
        }
    }
}

// ---------------- Flash attention (causal) + residual ----------------
// KV-SPLIT, 2048 blocks x 256 threads (4 waves).  Each block owns 32
// q-rows of one head; wave w processes kv tiles t = w, w+4, ... (stripe
// partition -- no K/V read duplication).  Compute loop is BARRIER-FREE:
// K/V fragments read direct from global (L2-resident: bid%8 -> bh%8
// confines each XCD to 4 heads = 2MB < 4MB L2), K prefetched one owned
// tile ahead, P through per-wave private 4KB swizzled LDS.
// UNNORMALIZED softmax (p = exp2(s), no max state) makes the kv-stripe
// merge pure addition: one LDS exchange + 2 barriers per block TOTAL.
// l accumulated by ones-row MFMA (zero VALU row-sum work).
// R2 POST-MORTEM: __launch_bounds__(256,4) capped regs at 128/wave ->
// fragment arrays spilled to scratch -> 442MB HBM writes, 177us.  Fix:
// (256,2) cap=256 (no spill, ~160 live peak), and V-fragment loads moved
// AFTER the P-pack so vb is not live across QK^T (peak pressure -30).
__global__ __launch_bounds__(256, 2) void attn_kernel(
    const unsigned short* __restrict__ QKVh, const float* __restrict__ Qin,
    float* __restrict__ out)
{
    const int bid = blockIdx.x;          // 0..2047
    const int bh  = bid & 31;            // head-batch (bh%8 == XCD)
    const int qg  = 63 - (bid >> 5);     // 32-row q-group, heavy jobs first
    const int q0  = qg * 32;
    const int nt  = (qg >> 1) + 1;       // causal tile count
    const int tdiag = nt - 1;            // diagonal tile (== q0>>6)
    const int tid  = threadIdx.x;
    const int lane = tid & 63;
    const int w    = tid >> 6;           // 0..3 = kv stripe
    const int l15 = lane & 15, lhi = lane >> 4;
    const int rxor = (l15 & 7) << 4;

    const size_t headOff = (size_t)bh * N_ * D_;
    const unsigned short* qp = QKVh + headOff;                      // [N][D]
    const unsigned short* kh = QKVh + (size_t)M_TOT * E_ + headOff; // [N][D]
    const unsigned short* vh = QKVh + (size_t)2 * M_TOT * E_ + headOff; // [D][N]

    __shared__ union {
        unsigned short P[4][2048];       // per-wave P buffer (4KB each)
        struct {
            f32x4 Mo[4][8][64];          // partial O  [wave][qh*4+n][lane]
            float Ml[4][2][64];          // partial l  [wave][qh][lane]
        } m;
    } sm;                                 // 34816 B

    // Q fragments: B-operand, col = q-row (q0 + qh*16 + l15), k = d
    bf16x8 qf[2][2];
    #pragma unroll
    for (int qh = 0; qh < 2; qh++)
        #pragma unroll
        for (int ks = 0; ks < 2; ks++)
            qf[qh][ks] = *(const bf16x8*)(qp
                + (size_t)(q0 + qh*16 + l15) * D_ + ks*32 + lhi*8);

    // per-lane intra-tile byte offsets
    // K frag (ks,n) @ tile t: (t*64 + n*16 + l15)*128 + ks*64 + lhi*16
    const char* kbase = (const char*)kh + l15*128 + lhi*16;
    // V frag (ks,n) @ tile t: (n*16 + l15)*4096 + t*128 + ks*64 + lhi*16
    const char* vbase = (const char*)vh + l15*4096 + lhi*16;

    const f32x4 fz = {0.f, 0.f, 0.f, 0.f};
    f32x4 o[2][4], ol[2];
    #pragma unroll
    for (int qh = 0; qh < 2; qh++) {
        ol[qh] = fz;
        #pragma unroll
        for (int n = 0; n < 4; n++) o[qh][n] = fz;
    }
    bf16x8 ones;
    #pragma unroll
    for (int i = 0; i < 8; i++) ones[i] = (short)0x3F80;   // bf16 1.0

    // preload K for this wave's first tile
    bf16x8 kb[2][4];
    if (w < nt) {
        const char* kt0 = kbase + (size_t)w * 8192;
        #pragma unroll
        for (int ks = 0; ks < 2; ks++)
            #pragma unroll
            for (int n = 0; n < 4; n++)
                kb[ks][n] = *(const bf16x8*)(kt0 + n*2048 + ks*64);
    }

    char* pw = (char*)sm.P[w];

    #pragma unroll 1
    for (int t = w; t < nt; t += 4) {
        // QK^T swapped: S^T = K * Q^T  (lane: q = l15, kv = n*16+lhi*4+j)
        f32x4 sf[2][4];
        __builtin_amdgcn_s_setprio(1);
        #pragma unroll
        for (int qh = 0; qh < 2; qh++)
            #pragma unroll
            for (int n = 0; n < 4; n++)
                sf[qh][n] = __builtin_amdgcn_mfma_f32_16x16x32_bf16(
                    kb[1][n], qf[qh][1],
                    __builtin_amdgcn_mfma_f32_16x16x32_bf16(
                        kb[0][n], qf[qh][0], fz, 0, 0, 0), 0, 0, 0);
        __builtin_amdgcn_s_setprio(0);

        if (t == tdiag) {   // causal mask, diagonal tile only
            #pragma unroll
            for (int qh = 0; qh < 2; qh++) {
                const int qr = q0 + qh*16 + l15;
                #pragma unroll
                for (int n = 0; n < 4; n++)
                    #pragma unroll
                    for (int j = 0; j < 4; j++) {
                        const int kvc = t*64 + n*16 + lhi*4 + j;
                        sf[qh][n][j] = (kvc > qr) ? -1e30f : sf[qh][n][j];
                    }
            }
        }

        // p = exp2(s); pack pairs -> bf16, store to swizzled P rows
        #pragma unroll
        for (int qh = 0; qh < 2; qh++) {
            const int prow = (qh*16 + l15) * 128;
            #pragma unroll
            for (int n = 0; n < 4; n++) {
                unsigned int u0 = __float_as_uint(exp2f(sf[qh][n][0])) + 0x8000u;
                unsigned int u1 = __float_as_uint(exp2f(sf[qh][n][1])) + 0x8000u;
                unsigned int u2 = __float_as_uint(exp2f(sf[qh][n][2])) + 0x8000u;
                unsigned int u3 = __float_as_uint(exp2f(sf[qh][n][3])) + 0x8000u;
                uint2 pk;
                pk.x = __builtin_amdgcn_perm(u1, u0, 0x07060302u);
                pk.y = __builtin_amdgcn_perm(u3, u2, 0x07060302u);
                *(uint2*)(pw + prow + ((n*32 + lhi*8) ^ rxor)) = pk;
            }
        }

        // V fragments for this tile (issued post-QK: not live across sf)
        const char* vt = vbase + t*128;
        bf16x8 vb[2][4];
        #pragma unroll
        for (int ks = 0; ks < 2; ks++)
            #pragma unroll
            for (int n = 0; n < 4; n++)
                vb[ks][n] = *(const bf16x8*)(vt + n*65536 + ks*64);

        // prefetch K for next owned tile (t+4); flies during PV
        if (t + 4 < nt) {
            const char* kt = kbase + (size_t)(t + 4) * 8192;
            #pragma unroll
            for (int ks = 0; ks < 2; ks++)
                #pragma unroll
                for (int n = 0; n < 4; n++)
                    kb[ks][n] = *(const bf16x8*)(kt + n*2048 + ks*64);
        }

        // PV: O^T += V^T * P^T ; l += ones-row * P^T (same pb operands)
        #pragma unroll
        for (int ks = 0; ks < 2; ks++) {
            bf16x8 pb[2];
            #pragma unroll
            for (int qh = 0; qh < 2; qh++)
                pb[qh] = *(const bf16x8*)(pw + (qh*16 + l15)*128
                                             + ((ks*64 + lhi*16) ^ rxor));
            __builtin_amdgcn_s_setprio(1);
            #pragma unroll
            for (int n = 0; n < 4; n++) {
                o[0][n] = __builtin_amdgcn_mfma_f32_16x16x32_bf16(
                    vb[ks][n], pb[0], o[0][n], 0, 0, 0);
                o[1][n] = __builtin_amdgcn_mfma_f32_16x16x32_bf16(
                    vb[ks][n], pb[1], o[1][n], 0, 0, 0);
            }
            ol[0] = __builtin_amdgcn_mfma_f32_16x16x32_bf16(
                ones, pb[0], ol[0], 0, 0, 0);
            ol[1] = __builtin_amdgcn_mfma_f32_16x16x32_bf16(
                ones, pb[1], ol[1], 0, 0, 0);
            __builtin_amdgcn_s_setprio(0);
        }
    }

    // ---- merge kv stripes (pure addition; unnormalized softmax) ----
    __syncthreads();                     // all P reads done (merge aliases P)
    #pragma unroll
    for (int qh = 0; qh < 2; qh++) {
        #pragma unroll
        for (int n = 0; n < 4; n++)
            sm.m.Mo[w][qh*4 + n][lane] = o[qh][n];
        sm.m.Ml[w][qh][lane] = ol[qh][0];   // all acc rows equal; [0] = l(q)
    }
    __syncthreads();

    // epilogue: wave w handles fragment pairs p = 2w, 2w+1  (p = qh*4+n)
    const int bb = bh >> 4, hh = bh & 15;
    #pragma unroll
    for (int pi = 0; pi < 2; pi++) {
        const int p  = 2*w + pi;
        const int qh = p >> 2, n = p & 3;
        f32x4 acc = sm.m.Mo[0][p][lane];
        float ls  = sm.m.Ml[0][qh][lane];
        #pragma unroll
        for (int w2 = 1; w2 < 4; w2++) {
            acc += sm.m.Mo[w2][p][lane];
            ls  += sm.m.Ml[w2][qh][lane];
        }
        const float linv = 1.0f / ls;
        const int qr = q0 + qh*16 + l15;
        const int d0 = n*16 + lhi*4;
        const size_t idx = ((size_t)(bb * N_ + qr)) * E_ + hh * D_ + d0;
        const float4 r = *(const float4*)(Qin + idx);
        float4 ov;
        ov.x = acc[0] * linv + r.x;
        ov.y = acc[1] * linv + r.y;
        ov.z = acc[2] * linv + r.z;
        ov.w = acc[3] * linv + r.w;
        *(float4*)(out + idx) = ov;
    }
}

extern "C" void kernel_launch(void* const* d_in, const int* in_sizes, int n_in,
                              void* d_out, int out_size, void* d_ws, size_t ws_size,
                              hipStream_t stream) {
    const float* Q     = (const float*)d_in[0];
    const float* K     = (const float*)d_in[1];
    const float* V     = (const float*)d_in[2];
    // d_in[3] = mask (causal, implemented analytically) -- unused
    const float* Wq    = (const float*)d_in[4];
    const float* bq    = (const float*)d_in[5];
    const float* Wk    = (const float*)d_in[6];
    const float* bk    = (const float*)d_in[7];
    const float* Wv    = (const float*)d_in[8];
    const float* bv    = (const float*)d_in[9];
    const float* gamma = (const float*)d_in[10];
    const float* beta  = (const float*)d_in[11];
    float* out = (float*)d_out;

    char* ws = (char*)d_ws;
    unsigned short* Xn   = (unsigned short*)ws;                    // 3*4096*1024 bf16 = 25,165,824 B
    unsigned short* Wt   = (unsigned short*)(ws + 25165824);       // 3*1024*1024 bf16 =  6,291,456 B
    unsigned short* QKVh = (unsigned short*)(ws + 31457280);       // 3*4096*1024 bf16 = 25,165,824 B

    ln_kernel  <<<dim3(4096, 3),   256,        0, stream>>>(Q, K, V, gamma, beta, Xn);
    wt_kernel  <<<dim3(32, 32, 3), dim3(32,8), 0, stream>>>(Wq, Wk, Wv, Wt);
    gemm_kernel<<<dim3(768),       256,        0, stream>>>(Xn, Wt, bq, bk, bv, QKVh);
    attn_kernel<<<dim3(2048),      256,        0, stream>>>(QKVh, Q, out);
}

// Round 4
// 93.398 us; speedup vs baseline: 2.3776x; 1.2838x over previous
//
#include <hip/hip_runtime.h>
#include <hip/hip_bf16.h>

#define B_ 2
#define N_ 2048
#define E_ 1024
#define H_ 16
#define D_ 64
#define M_TOT (B_*N_)   // 4096

typedef __attribute__((ext_vector_type(8))) short bf16x8;
typedef __attribute__((ext_vector_type(4))) float f32x4;

__device__ __forceinline__ unsigned short f2bf(float f) {
    unsigned int u = __float_as_uint(f);
    u += 0x7fff + ((u >> 16) & 1);   // round-to-nearest-even
    return (unsigned short)(u >> 16);
}

// async global->LDS, 16B per lane; dst is wave-uniform base + lane*16
__device__ __forceinline__ void gload16(const void* g, void* l) {
    __builtin_amdgcn_global_load_lds(
        (const __attribute__((address_space(1))) unsigned int*)g,
        (__attribute__((address_space(3))) unsigned int*)l, 16, 0, 0);
}

// ---------------- LayerNorm -> bf16, PRE-SWIZZLED rows ----------------
// Xn[row][byte'] where byte' = byte ^ ((row&7)<<4) within each 128B chunk.
__global__ __launch_bounds__(256) void ln_kernel(
    const float* __restrict__ Q, const float* __restrict__ K,
    const float* __restrict__ V, const float* __restrict__ gamma,
    const float* __restrict__ beta, unsigned short* __restrict__ Xn)
{
    const int row = blockIdx.x;          // 0..4095
    const int s   = blockIdx.y;          // 0: Q, 1: K, 2: V
    const float* X = (s == 0) ? Q : (s == 1) ? K : V;
    const int tid = threadIdx.x;
    const float4 x = ((const float4*)(X + (size_t)row * E_))[tid];
    float sum = x.x + x.y + x.z + x.w;
    float sq  = x.x*x.x + x.y*x.y + x.z*x.z + x.w*x.w;
    #pragma unroll
    for (int off = 32; off > 0; off >>= 1) {
        sum += __shfl_down(sum, off);
        sq  += __shfl_down(sq,  off);
    }
    __shared__ float red[8];
    const int wid = tid >> 6;
    if ((tid & 63) == 0) { red[wid] = sum; red[4 + wid] = sq; }
    __syncthreads();
    if (tid == 0) {
        float s0 = red[0] + red[1] + red[2] + red[3];
        float q0 = red[4] + red[5] + red[6] + red[7];
        red[0] = s0 * (1.0f / E_);
        red[4] = q0 * (1.0f / E_);
    }
    __syncthreads();
    const float mean = red[0];
    const float var  = red[4] - mean * mean;
    const float inv  = rsqrtf(var + 1e-5f);
    const float4 g = ((const float4*)gamma)[tid];
    const float4 b = ((const float4*)beta)[tid];
    ushort4 o;
    o.x = f2bf((x.x - mean) * inv * g.x + b.x);
    o.y = f2bf((x.y - mean) * inv * g.y + b.y);
    o.z = f2bf((x.z - mean) * inv * g.z + b.z);
    o.w = f2bf((x.w - mean) * inv * g.w + b.w);
    const int bo = 8 * tid;
    const int bs = (bo & ~127) | ((bo & 127) ^ ((row & 7) << 4));
    char* rowp = (char*)(Xn + (size_t)s * M_TOT * E_ + (size_t)row * E_);
    *(ushort4*)(rowp + bs) = o;
}

// ------- Weight transpose + bf16, PRE-SWIZZLED: Wt[s][n][k'] = W_s[k][n] -----
__global__ __launch_bounds__(256) void wt_kernel(
    const float* __restrict__ Wq, const float* __restrict__ Wk,
    const float* __restrict__ Wv, unsigned short* __restrict__ Wt)
{
    const int s = blockIdx.z;
    const float* W = (s == 0) ? Wq : (s == 1) ? Wk : Wv;
    __shared__ float tile[32][33];
    const int tx = threadIdx.x, ty = threadIdx.y;   // 32 x 8
    const int n0 = blockIdx.x * 32, k0 = blockIdx.y * 32;
    #pragma unroll
    for (int i = 0; i < 4; i++)
        tile[ty + 8*i][tx] = W[(size_t)(k0 + ty + 8*i) * E_ + n0 + tx];
    __syncthreads();
    unsigned short* dst = Wt + (size_t)s * E_ * E_;
    #pragma unroll
    for (int i = 0; i < 4; i++) {
        const int n = n0 + ty + 8*i;
        const int bo = 2 * (k0 + tx);
        const int bs = (bo & ~127) | ((bo & 127) ^ ((n & 7) << 4));
        *(unsigned short*)((char*)(dst + (size_t)n * E_) + bs) =
            f2bf(tile[tx][ty + 8*i]);
    }
}

// --- GEMM: C = Xn[s] @ W_s + b_s -> head layout bf16 ---   (R23-proven)
//   128x128 tile, 4 waves in a 1x4 grid -> per-wave 128 rows x 32 cols.
//   A: gload_lds dbuf (32KB LDS -> 3 blocks/CU, grid 768, T1 map).
//   B: direct global->reg, issued immediately pre-barrier.
//   s=2 epilogue: 4 consecutive nseq packed into one 8B store.
__global__ __launch_bounds__(256, 3) void gemm_kernel(
    const unsigned short* __restrict__ Xn, const unsigned short* __restrict__ Wt,
    const float* __restrict__ bq, const float* __restrict__ bk,
    const float* __restrict__ bv, unsigned short* __restrict__ QKVh)
{
    const int bid = blockIdx.x;
    const int wk  = (bid & 7) * 96 + (bid >> 3);   // bijective, 768 = 8*96
    const int s   = wk >> 8;            // 0..2
    const int rem = wk & 255;
    const int m0  = (rem >> 3) * 128;
    const int n0  = (rem & 7) * 128;
    const float* bias = (s == 0) ? bq : (s == 1) ? bk : bv;
    const unsigned short* A  = Xn + (size_t)s * M_TOT * E_;
    const unsigned short* Bw = Wt + (size_t)s * E_ * E_;
    unsigned short* out = QKVh + (size_t)s * M_TOT * E_;
    const int tid = threadIdx.x;
    const int lane = tid & 63;
    const int w = tid >> 6;             // 0..3  (wave = 32-col panel)
    const int l15 = lane & 15, lhi = lane >> 4;

    __shared__ unsigned short Al[2][128][64];   // 16KB per buf

    const int srow = lane >> 3;        // 0..7
    const int scol = (lane & 7) * 8;   // elem col (source is pre-swizzled)
    const int rx = (l15 & 7) << 4;     // read-side XOR

    // B fragment base: row n0 + w*32 + n*16 + l15  (row&7 == l15&7 -> rx)
    const char* bbase = (const char*)Bw + (size_t)(n0 + w*32 + l15) * (E_ * 2);

    f32x4 acc[8][2];
    #pragma unroll
    for (int m = 0; m < 8; m++)
        #pragma unroll
        for (int n = 0; n < 2; n++)
            acc[m][n] = (f32x4){0.f, 0.f, 0.f, 0.f};

    // stage A k-tile kt into buffer b: per wave 4 gload16 (32 rows)
    #define STAGEA(b_, kt_) do {                                             \
        const int k0_ = (kt_) * 64;                                          \
        _Pragma("unroll")                                                    \
        for (int ii = 0; ii < 4; ii++) {                                     \
            const int r_ = w*32 + ii*8;                                      \
            gload16(A + (size_t)(m0 + r_ + srow) * E_ + k0_ + scol,          \
                    &Al[b_][r_][0]);                                         \
        }                                                                    \
    } while (0)

    STAGEA(0, 0);
    for (int kt = 0; kt < 16; kt++) {
        const int buf = kt & 1;
        // B fragments for this k-step: direct from global (L2-hot)
        bf16x8 bfr[2][2];
        #pragma unroll
        for (int ks = 0; ks < 2; ks++)
            #pragma unroll
            for (int n = 0; n < 2; n++)
                bfr[ks][n] = *(const bf16x8*)(bbase + (size_t)n * 16 * (E_ * 2)
                               + kt*128 + ((ks*64 + lhi*16) ^ rx));
        __syncthreads();                 // A buf staged (vmcnt drained here)
        if (kt + 1 < 16) STAGEA(buf ^ 1, kt + 1);  // async, flies during compute
        const char* ab = (const char*)Al[buf];
        #pragma unroll
        for (int ks = 0; ks < 2; ks++) {
            #pragma unroll
            for (int m = 0; m < 8; m++) {
                bf16x8 af = *(const bf16x8*)(ab
                        + (m*16 + l15)*128 + ((ks*64 + lhi*16) ^ rx));
                #pragma unroll
                for (int n = 0; n < 2; n++)
                    acc[m][n] = __builtin_amdgcn_mfma_f32_16x16x32_bf16(
                        af, bfr[ks][n], acc[m][n], 0, 0, 0);
            }
        }
    }
    #undef STAGEA

    const float scale = (s == 0) ? 0.18033688011112042f : 1.0f;
    #pragma unroll
    for (int n = 0; n < 2; n++) {
        const int gn = n0 + w*32 + n*16 + l15;
        const float bv_ = bias[gn];
        const int h = gn >> 6, d = gn & 63;
        #pragma unroll
        for (int m = 0; m < 8; m++) {
            const int gmBase = m0 + m*16 + lhi*4;
            if (s == 2) {
                // 4 consecutive nseq -> one packed 8B store
                const int bb2 = gmBase >> 11, nseq = gmBase & 2047;
                ushort4 pk;
                pk.x = f2bf(acc[m][n][0] + bv_);
                pk.y = f2bf(acc[m][n][1] + bv_);
                pk.z = f2bf(acc[m][n][2] + bv_);
                pk.w = f2bf(acc[m][n][3] + bv_);
                *(ushort4*)(out + ((size_t)(bb2*H_ + h) * D_ + d) * N_ + nseq)
                    = pk;
            } else {
                #pragma unroll
                for (int j = 0; j < 4; j++) {
                    const int gm = gmBase + j;
                    const int bb2 = gm >> 11, nseq = gm & 2047;
                    out[((size_t)(bb2*H_ + h) * N_ + nseq) * D_ + d] =
                        f2bf((acc[m][n][j] + bv_) * scale);
                }
            }
        }
    }
}

// ---------------- Flash attention (causal) + residual ----------------
// R0-PROVEN STRUCTURE (LDS-staged K/V, barrier-pipelined prefetch), with
// two surgical changes:
//   (a) SINGLE-PASS blocks: grid 1024, block = (bh, g); g = 31-(bid>>5)
//       heavy-first (LPT packing).  bh = bid&31 keeps bid%8 == bh%8 so
//       each XCD still sees only 4 heads (2MB K/V < 4MB L2).
//   (b) ones-row MFMA for the softmax denominator (l = mfma(ones, P),
//       accumulated with O) -- removes the per-tile 16 adds + 2
//       ds_bpermute shuffles from the serial VALU path; MFMA pipe is
//       ~14% busy, it's free there.  Numerics: l is the exact sum of the
//       same bf16-rounded P used for PV (proven in R1/R3, absmax equal).
// R1/R3 post-mortem: direct-from-global K/V (no staging) exposed V-load
// latency on the critical path every tile; occupancy 2.2x'd but time
// barely moved.  The R0 barrier pipeline hides staging under a full
// compute phase -- keep it.
// 1024 blocks x 512 threads (8 waves = 4 rowgroups x 2 kv-halves).
// UNNORMALIZED softmax: p = exp2(s) directly; uniform scale cancels in
// o/l.  Swapped QK^T, T5 setprio, flash-merge = l0+l1.
__global__ __launch_bounds__(512, 4) void attn_kernel(
    const unsigned short* __restrict__ QKVh, const float* __restrict__ Qin,
    float* __restrict__ out)
{
    const int bid  = blockIdx.x;        // 0..1023
    const int slot = bid >> 5;          // 0..31
    const int bh   = bid & 31;          // head-batch (bh%8 == XCD)
    const int g    = 31 - slot;         // 64-row q-group, heavy jobs first
    const int q0   = g * 64;
    const int S    = (g + 2) >> 1;      // super-iterations (kv tile pairs)
    const int tid = threadIdx.x;
    const int lane = tid & 63;
    const int w = tid >> 6;             // 0..7
    const int h = w >> 2;               // kv-half
    const int rg = w & 3;               // rowgroup
    const int l15 = lane & 15, lhi = lane >> 4;
    const size_t headOff = (size_t)bh * N_ * D_;
    const unsigned short* qh = QKVh + headOff;
    const unsigned short* kh = QKVh + (size_t)M_TOT * E_ + headOff;
    const unsigned short* vh = QKVh + (size_t)2 * M_TOT * E_ + headOff; // [D][N]

    __shared__ unsigned short Kt[2][64*64];   // [tile-parity][kv][d] swizzled
    __shared__ unsigned short Vt[2][64*64];   // [tile-parity][d][kv] swizzled
    __shared__ unsigned short Pl[8][16*64];   // per-wave P rows (doubles as
                                              // f32 O-merge buffer, 16KB)
    __shared__ float Ml[4][16];               // per-rowgroup l of half 1

    // staging: 512 threads cover one 64x64 bf16 tile with 1 uint4 each
    const int sr  = (tid >> 3) & 63;   // 0..63
    const int sce = (tid & 7) * 8;     // elem col
    const int wofs = sr * 128 + (((tid & 7) * 16) ^ ((sr & 7) << 4)); // byte
    const int rxor = (l15 & 7) << 4;   // read-side XOR

    const int bb = bh >> 4, hh = bh & 15;
    const int wlo = q0 + rg * 16;       // rowgroup's first q-row

    // prologue: stage tiles 0,1
    {
        uint4 ka  = *(const uint4*)(kh + (size_t)sr * D_ + sce);
        uint4 kb2 = *(const uint4*)(kh + (size_t)(64 + sr) * D_ + sce);
        uint4 va  = *(const uint4*)(vh + (size_t)sr * N_ + sce);
        uint4 vb2 = *(const uint4*)(vh + (size_t)sr * N_ + 64 + sce);
        *(uint4*)((char*)Kt[0] + wofs) = ka;
        *(uint4*)((char*)Kt[1] + wofs) = kb2;
        *(uint4*)((char*)Vt[0] + wofs) = va;
        *(uint4*)((char*)Vt[1] + wofs) = vb2;
    }

    bf16x8 qf[2];
    #pragma unroll
    for (int ks = 0; ks < 2; ks++)
        qf[ks] = *(const bf16x8*)(qh + (size_t)(wlo + l15) * D_
                                      + ks*32 + lhi*8);

    const f32x4 fz = {0.f, 0.f, 0.f, 0.f};
    f32x4 o[4], ol;
    #pragma unroll
    for (int n = 0; n < 4; n++) o[n] = fz;
    ol = fz;
    bf16x8 ones;
    #pragma unroll
    for (int i = 0; i < 8; i++) ones[i] = (short)0x3F80;   // bf16 1.0

    #pragma unroll 1
    for (int s = 0; s < S; s++) {
        __syncthreads();             // staged pair visible
        // prefetch next pair (T14: loads fly during compute, write after
        // the reads-done barrier)
        uint4 nka, nkb, nva, nvb;
        const bool pre = (s + 1 < S);
        if (pre) {
            const int kvn = (s + 1) * 128;
            nka = *(const uint4*)(kh + (size_t)(kvn + sr) * D_ + sce);
            nkb = *(const uint4*)(kh + (size_t)(kvn + 64 + sr) * D_ + sce);
            nva = *(const uint4*)(vh + (size_t)sr * N_ + kvn + sce);
            nvb = *(const uint4*)(vh + (size_t)sr * N_ + kvn + 64 + sce);
        }
        const int t = 2*s + h;
        if (t <= g) {
            const int kv0 = t * 64;
            const char* kbb = (const char*)Kt[t & 1];
            const char* vbb = (const char*)Vt[t & 1];
            // QK^T swapped: S^T = K * Q^T   (lane: q=l15, kv=16n+4lhi+j)
            f32x4 sfr[4];
            #pragma unroll
            for (int n = 0; n < 4; n++) sfr[n] = fz;
            #pragma unroll
            for (int ks = 0; ks < 2; ks++) {
                bf16x8 kb[4];
                #pragma unroll
                for (int n = 0; n < 4; n++)
                    kb[n] = *(const bf16x8*)(kbb + (n*16 + l15)*128
                                                 + ((ks*64 + lhi*16) ^ rxor));
                __builtin_amdgcn_s_setprio(1);
                #pragma unroll
                for (int n = 0; n < 4; n++)
                    sfr[n] = __builtin_amdgcn_mfma_f32_16x16x32_bf16(
                        kb[n], qf[ks], sfr[n], 0, 0, 0);
                __builtin_amdgcn_s_setprio(0);
            }
            const int qr = wlo + l15;
            if (t == g) {   // diagonal tile: causal mask
                #pragma unroll
                for (int n = 0; n < 4; n++)
                    #pragma unroll
                    for (int j = 0; j < 4; j++) {
                        int kvc = kv0 + n*16 + lhi*4 + j;
                        sfr[n][j] = (kvc > qr) ? -1e30f : sfr[n][j];
                    }
            }
            // unnormalized softmax: p = exp2(s); l via ones-MFMA in PV
            // P store: lane owns row q=l15; natural kv order, 8B writes
            char* pw = (char*)Pl[w];
            #pragma unroll
            for (int n = 0; n < 4; n++) {
                unsigned int u0 = __float_as_uint(exp2f(sfr[n][0])) + 0x8000u;
                unsigned int u1 = __float_as_uint(exp2f(sfr[n][1])) + 0x8000u;
                unsigned int u2 = __float_as_uint(exp2f(sfr[n][2])) + 0x8000u;
                unsigned int u3 = __float_as_uint(exp2f(sfr[n][3])) + 0x8000u;
                uint2 pk;
                pk.x = __builtin_amdgcn_perm(u1, u0, 0x07060302u);
                pk.y = __builtin_amdgcn_perm(u3, u2, 0x07060302u);
                *(uint2*)(pw + l15*128 + ((n*32 + lhi*8) ^ rxor)) = pk;
            }
            // PV: O^T += V^T * P^T ; l += ones-row * P^T (same pb operand)
            #pragma unroll
            for (int ks = 0; ks < 2; ks++) {
                bf16x8 pb = *(const bf16x8*)(pw + l15*128
                                             + ((ks*64 + lhi*16) ^ rxor));
                bf16x8 vbr[4];
                #pragma unroll
                for (int n = 0; n < 4; n++)
                    vbr[n] = *(const bf16x8*)(vbb + (n*16 + l15)*128
                                                  + ((ks*64 + lhi*16) ^ rxor));
                __builtin_amdgcn_s_setprio(1);
                #pragma unroll
                for (int n = 0; n < 4; n++)
                    o[n] = __builtin_amdgcn_mfma_f32_16x16x32_bf16(
                        vbr[n], pb, o[n], 0, 0, 0);
                ol = __builtin_amdgcn_mfma_f32_16x16x32_bf16(
                    ones, pb, ol, 0, 0, 0);
                __builtin_amdgcn_s_setprio(0);
            }
        }
        __syncthreads();             // all reads of staged pair done
        if (pre) {
            *(uint4*)((char*)Kt[0] + wofs) = nka;
            *(uint4*)((char*)Kt[1] + wofs) = nkb;
            *(uint4*)((char*)Vt[0] + wofs) = nva;
            *(uint4*)((char*)Vt[1] + wofs) = nvb;
        }
    }

    // ---- flash-merge halves + output (P area is dead; reuse as f32) ----
    // ol rows all equal Sum_kv P[kv][q]; l_i = ol[0], replicated over lhi.
    const float l_i = ol[0];
    __syncthreads();
    if (h == 1) {
        char* ob = (char*)Pl + rg * 4096;
        #pragma unroll
        for (int n = 0; n < 4; n++)
            *(f32x4*)(ob + l15*256 + ((n*64 + lhi*16) ^ rxor)) = o[n];
        if (lhi == 0) Ml[rg][l15] = l_i;
    }
    __syncthreads();
    if (h == 0) {
        const float linv = 1.0f / (l_i + Ml[rg][l15]);
        const char* ob = (const char*)Pl + rg * 4096;
        const int qr = wlo + l15;
        #pragma unroll
        for (int n = 0; n < 4; n++) {
            f32x4 o1 = *(const f32x4*)(ob + l15*256 + ((n*64 + lhi*16) ^ rxor));
            const int d0 = n*16 + lhi*4;
            size_t idx = ((size_t)(bb * N_ + qr)) * E_ + hh * D_ + d0;
            float4 r = *(const float4*)(Qin + idx);
            float4 ov;
            ov.x = (o[n][0] + o1[0]) * linv + r.x;
            ov.y = (o[n][1] + o1[1]) * linv + r.y;
            ov.z = (o[n][2] + o1[2]) * linv + r.z;
            ov.w = (o[n][3] + o1[3]) * linv + r.w;
            *(float4*)(out + idx) = ov;
        }
    }
}

extern "C" void kernel_launch(void* const* d_in, const int* in_sizes, int n_in,
                              void* d_out, int out_size, void* d_ws, size_t ws_size,
                              hipStream_t stream) {
    const float* Q     = (const float*)d_in[0];
    const float* K     = (const float*)d_in[1];
    const float* V     = (const float*)d_in[2];
    // d_in[3] = mask (causal, implemented analytically) -- unused
    const float* Wq    = (const float*)d_in[4];
    const float* bq    = (const float*)d_in[5];
    const float* Wk    = (const float*)d_in[6];
    const float* bk    = (const float*)d_in[7];
    const float* Wv    = (const float*)d_in[8];
    const float* bv    = (const float*)d_in[9];
    const float* gamma = (const float*)d_in[10];
    const float* beta  = (const float*)d_in[11];
    float* out = (float*)d_out;

    char* ws = (char*)d_ws;
    unsigned short* Xn   = (unsigned short*)ws;                    // 3*4096*1024 bf16 = 25,165,824 B
    unsigned short* Wt   = (unsigned short*)(ws + 25165824);       // 3*1024*1024 bf16 =  6,291,456 B
    unsigned short* QKVh = (unsigned short*)(ws + 31457280);       // 3*4096*1024 bf16 = 25,165,824 B

    ln_kernel  <<<dim3(4096, 3),   256,        0, stream>>>(Q, K, V, gamma, beta, Xn);
    wt_kernel  <<<dim3(32, 32, 3), dim3(32,8), 0, stream>>>(Wq, Wk, Wv, Wt);
    gemm_kernel<<<dim3(768),       256,        0, stream>>>(Xn, Wt, bq, bk, bv, QKVh);
    attn_kernel<<<dim3(1024),      512,        0, stream>>>(QKVh, Q, out);
}